// Round 2
// baseline (76.004 us; speedup 1.0000x reference)
//
#include <hip/hip_runtime.h>

#define BATCH 256
#define HWSZ  4096          // 64*64

// One block = 256 threads = 4 waves; each WAVE owns one (h,w) column and holds
// that column's ENTIRE circular batch chain (256 rows) in registers: lane l
// keeps rows 4l..4l+3. The roll is along batch only, so the 4-layer recurrence
// needs just rows 4l+4, 4l+5 per layer = lane (l+1)&63's first two registers
// -> 2 intra-wave shuffles per layer. Zero LDS and zero barriers inside the
// 4-layer loop; no halo recompute; grid = 1024 blocks (4/CU, 4 waves/SIMD).
// LDS is only a one-time transpose stage: coalesced float4 x-load -> register
// layout, and register outputs -> coalesced float4 store.
__global__ __launch_bounds__(256, 4) void fused_kernel(
    const float* __restrict__ x,         // [256][4096]
    const float* __restrict__ tg,        // [4][16][4096]
    float* __restrict__ out,             // [256][4096]
    float* __restrict__ partials)        // [1024] per-block reg sums
{
    __shared__ float xs[BATCH * 5];      // [row][col0..3], stride 5: gcd(5,32)=1
    __shared__ float tws[256];           // sigmoid(tg): [l][p][col] = (l*16+p)*4+col
    __shared__ float wsum[4];

    const int tid  = threadIdx.x;
    const int w    = tid >> 6;           // wave id = column within block
    const int lane = tid & 63;
    const int nxt  = (lane + 1) & 63;
    const int hw0  = blockIdx.x * 4;

    // Stage sigmoid(tg): 4*16 patterns x 4 cols = 256 values, one per thread.
    {
        int lp = tid >> 2, cc = tid & 3;
        float g = tg[lp * HWSZ + hw0 + cc];
        tws[lp * 4 + cc] = 1.0f / (1.0f + __expf(-g));
    }
    // Stage x: thread tid loads row tid's 4 columns as float4 (coalesced 16B),
    // transpose via LDS into the wave-chain register layout.
    {
        const float4 v = *reinterpret_cast<const float4*>(&x[tid * HWSZ + hw0]);
        xs[tid * 5 + 0] = v.x; xs[tid * 5 + 1] = v.y;
        xs[tid * 5 + 2] = v.z; xs[tid * 5 + 3] = v.w;
    }
    __syncthreads();

    float cur0 = xs[(4 * lane + 0) * 5 + w];
    float cur1 = xs[(4 * lane + 1) * 5 + w];
    float cur2 = xs[(4 * lane + 2) * 5 + w];
    float cur3 = xs[(4 * lane + 3) * 5 + w];

    float racc = 0.0f;

#pragma unroll
    for (int l = 0; l < 4; ++l) {
        // Per-layer sigmoid weights: wave-uniform LDS addresses -> broadcast.
        // Patterns 2/4, 3/5, 10/12, 11/13 share identical w_p -> pre-sum.
        const float* tl = &tws[l * 64 + w];      // stride 4 per pattern
        float T0  = tl[0 * 4], T1 = tl[1 * 4];
        float T24 = tl[2 * 4] + tl[4 * 4];
        float T35 = tl[3 * 4] + tl[5 * 4];
        float T6  = tl[6 * 4], T7 = tl[7 * 4];
        float T8  = tl[8 * 4], T9 = tl[9 * 4];
        float TAC = tl[10 * 4] + tl[12 * 4];
        float TBD = tl[11 * 4] + tl[13 * 4];
        float TE  = tl[14 * 4], TF = tl[15 * 4];

        // Neighbor rows 4l+4, 4l+5 from lane+1 (wraps the circular chain).
        float e4 = __shfl(cur0, nxt, 64);
        float e5 = __shfl(cur1, nxt, 64);

        auto elem = [&](float v0, float v1, float v2) -> float {
            float a0 = 1.0f - v0, a1 = 1.0f - v1, a2 = 1.0f - v2;
            float g0 = a1 * a1, g1 = a1 * v1, g2 = v1 * v1;
            float u00 = a0 * g0, u01 = a0 * g1, u02 = a0 * g2;
            float u10 = v0 * g0, u11 = v0 * g1, u12 = v0 * g2;

            float w0 = u00 * a2, w1 = u00 * v2;
            float w2 = u01 * a2, w3 = u01 * v2;   // == patterns 4,5
            float w6 = u02 * a2, w7 = u02 * v2;
            float w8 = u10 * a2, w9 = u10 * v2;
            float wA = u11 * a2, wB = u11 * v2;   // == patterns 12,13
            float wE = u12 * a2, wF = u12 * v2;

            float acc = w0 * T0 + w1 * T1 + w2 * T24 + w3 * T35
                      + w6 * T6 + w7 * T7 + w8 * T8 + w9 * T9
                      + wA * TAC + wB * TBD + wE * TE + wF * TF;

            if (l >= 1) {
                // sum_p log(w_p)   = 8 * log(v0*a0 * (v1*a1)^2 * v2*a2)
                // sum_p log(1-w_p) = log( prod_p (1-w_p) ), dups squared
                float s1 = (1.0f - w0) * (1.0f - w1) * (1.0f - w6) * (1.0f - w7)
                         * (1.0f - w8) * (1.0f - w9) * (1.0f - wE) * (1.0f - wF);
                float s2 = (1.0f - w2) * (1.0f - w3) * (1.0f - wA) * (1.0f - wB);
                float pB = s1 * s2 * s2;
                float pA = (v0 * a0) * (g1 * g1) * (v2 * a2);
                racc += 8.0f * __logf(pA) + __logf(pB);
            }
            return fminf(fmaxf(acc, 0.0f), 1.0f);
        };

        float o0 = elem(cur0, cur1, cur2);
        float o1 = elem(cur1, cur2, cur3);
        float o2 = elem(cur2, cur3, e4);
        float o3 = elem(cur3, e4, e5);
        cur0 = o0; cur1 = o1; cur2 = o2; cur3 = o3;
    }

    // Output transpose: registers -> LDS -> coalesced float4 store.
    __syncthreads();                     // xs reuse: all staging reads done
    xs[(4 * lane + 0) * 5 + w] = cur0;
    xs[(4 * lane + 1) * 5 + w] = cur1;
    xs[(4 * lane + 2) * 5 + w] = cur2;
    xs[(4 * lane + 3) * 5 + w] = cur3;
    __syncthreads();
    {
        float4 ov;
        ov.x = xs[tid * 5 + 0]; ov.y = xs[tid * 5 + 1];
        ov.z = xs[tid * 5 + 2]; ov.w = xs[tid * 5 + 3];
        *reinterpret_cast<float4*>(&out[tid * HWSZ + hw0]) = ov;
    }

    // Block reduction: wave shuffle (64) then cross-wave via LDS
#pragma unroll
    for (int off = 32; off; off >>= 1) racc += __shfl_down(racc, off, 64);
    if (lane == 0) wsum[w] = racc;
    __syncthreads();
    if (tid == 0)
        partials[blockIdx.x] = wsum[0] + wsum[1] + wsum[2] + wsum[3];
}

__global__ void finalize_kernel(const float* __restrict__ partials,
                                float* __restrict__ out_reg)
{
    int tid = threadIdx.x;                 // 256 threads, 1024 partials
    double v = 0.0;
#pragma unroll
    for (int k = 0; k < 4; ++k) v += (double)partials[tid + k * 256];
#pragma unroll
    for (int off = 32; off; off >>= 1) v += __shfl_down(v, off, 64);
    __shared__ double ws[4];
    if ((tid & 63) == 0) ws[tid >> 6] = v;
    __syncthreads();
    if (tid == 0) {
        double tot = ws[0] + ws[1] + ws[2] + ws[3];
        // reg = -(sum of logs)/(256*64*64*16), output reg/3
        out_reg[0] = (float)(-tot / (16777216.0 * 3.0));
    }
}

extern "C" void kernel_launch(void* const* d_in, const int* in_sizes, int n_in,
                              void* d_out, int out_size, void* d_ws, size_t ws_size,
                              hipStream_t stream)
{
    const float* x  = (const float*)d_in[0];   // (256,64,64)
    const float* tg = (const float*)d_in[1];   // (4,16,64,64)
    float* out      = (float*)d_out;           // 1048576 outputs + 1 reg
    float* partials = (float*)d_ws;            // 1024 floats

    fused_kernel<<<dim3(HWSZ / 4), dim3(256), 0, stream>>>(x, tg, out, partials);
    finalize_kernel<<<1, 256, 0, stream>>>(partials, out + (size_t)BATCH * HWSZ);
}